// Round 2
// baseline (366.201 us; speedup 1.0000x reference)
//
#include <hip/hip_runtime.h>
#include <hip/hip_bf16.h>
#include <stdint.h>

#define IN_FEATS 128
#define HID 256

typedef __bf16 bf16x8 __attribute__((ext_vector_type(8)));
typedef float  f32x4  __attribute__((ext_vector_type(4)));

// ---------------- Kernel 0: W1 [256][256] fp32 (k-major) -> W1T bf16 [n][k] ----
__global__ void k_prep(const float* __restrict__ W1, __bf16* __restrict__ W1T) {
    int k = blockIdx.x;      // 0..255  (input-feature index)
    int n = threadIdx.x;     // 0..255  (hidden index)
    W1T[(size_t)n * (2 * IN_FEATS) + k] = (__bf16)W1[(size_t)k * HID + n];
}

// ---------------- Kernel A: node projections -----------------------------------
// P_src[n,256] = h_src[n,:] @ W1[0:128,:]  + b1      (blockIdx.y == 0)
// P_dst[n,256] = h_dst[n,:] @ W1[128:256,:]          (blockIdx.y == 1)
// Block = 256 thr = 4 waves; block tile 32 rows x 256 cols; wave tile 32x64.
// mfma_f32_16x16x32_bf16; A frags converted fp32->bf16 in regs; B frags are
// 16B contiguous loads from W1T (L2-resident). No LDS, no barriers.
__global__ __launch_bounds__(256) void k_proj(
    const float* __restrict__ hs, const float* __restrict__ hd,
    const __bf16* __restrict__ W1T, const float* __restrict__ b1,
    __bf16* __restrict__ Ps, __bf16* __restrict__ Pd)
{
    const int which = blockIdx.y;
    const float* __restrict__ h = which ? hd : hs;
    __bf16* __restrict__ P = which ? Pd : Ps;
    const int koff = which ? IN_FEATS : 0;

    const int lane = threadIdx.x & 63;
    const int w    = threadIdx.x >> 6;   // wave 0..3
    const int n0   = w * 64;
    const int node0 = blockIdx.x * 32;
    const int qr = lane & 15;            // row (A) / col (B,D)
    const int qg = lane >> 4;            // k-group / D row-group

    f32x4 acc[2][4];
#pragma unroll
    for (int m = 0; m < 2; ++m)
#pragma unroll
        for (int n = 0; n < 4; ++n) acc[m][n] = (f32x4){0.f, 0.f, 0.f, 0.f};

#pragma unroll
    for (int ks = 0; ks < 4; ++ks) {
        const int k0 = ks * 32 + qg * 8;
        bf16x8 a[2];
#pragma unroll
        for (int m = 0; m < 2; ++m) {
            const float* ap = h + (size_t)(node0 + m * 16 + qr) * IN_FEATS + k0;
            float4 f0 = *(const float4*)ap;
            float4 f1 = *(const float4*)(ap + 4);
            bf16x8 t;
            t[0] = (__bf16)f0.x; t[1] = (__bf16)f0.y; t[2] = (__bf16)f0.z; t[3] = (__bf16)f0.w;
            t[4] = (__bf16)f1.x; t[5] = (__bf16)f1.y; t[6] = (__bf16)f1.z; t[7] = (__bf16)f1.w;
            a[m] = t;
        }
#pragma unroll
        for (int n = 0; n < 4; ++n) {
            const __bf16* bp = W1T + (size_t)(n0 + n * 16 + qr) * (2 * IN_FEATS) + koff + k0;
            bf16x8 b = *(const bf16x8*)bp;
#pragma unroll
            for (int m = 0; m < 2; ++m)
                acc[m][n] = __builtin_amdgcn_mfma_f32_16x16x32_bf16(a[m], b, acc[m][n], 0, 0, 0);
        }
    }

    // Epilogue: D layout col=lane&15, row=(lane>>4)*4+reg (m89-verified).
#pragma unroll
    for (int n = 0; n < 4; ++n) {
        const int col = n0 + n * 16 + qr;
        const float bias = which ? 0.f : b1[col];
#pragma unroll
        for (int m = 0; m < 2; ++m) {
            const int rowb = node0 + m * 16 + qg * 4;
#pragma unroll
            for (int i = 0; i < 4; ++i)
                P[(size_t)(rowb + i) * HID + col] = (__bf16)(acc[m][n][i] + bias);
        }
    }
}

// ---------------- Kernel B: edge scoring ---------------------------------------
// score[e] = b2 + sum_j relu(Ps[src[e]][j] + Pd[dst[e]][j]) * W2[j]
// Quarter-wave (16 lanes) per edge; lane q covers elems {8q..8q+7, 128+8q..+7}.
__device__ __forceinline__ float bflo(unsigned u) { return __uint_as_float(u << 16); }
__device__ __forceinline__ float bfhi(unsigned u) { return __uint_as_float(u & 0xffff0000u); }

__device__ __forceinline__ float dot8(uint4 s, uint4 d, float4 w0, float4 w1) {
    float r = 0.f, hv;
    hv = fmaxf(bflo(s.x) + bflo(d.x), 0.f); r = fmaf(hv, w0.x, r);
    hv = fmaxf(bfhi(s.x) + bfhi(d.x), 0.f); r = fmaf(hv, w0.y, r);
    hv = fmaxf(bflo(s.y) + bflo(d.y), 0.f); r = fmaf(hv, w0.z, r);
    hv = fmaxf(bfhi(s.y) + bfhi(d.y), 0.f); r = fmaf(hv, w0.w, r);
    hv = fmaxf(bflo(s.z) + bflo(d.z), 0.f); r = fmaf(hv, w1.x, r);
    hv = fmaxf(bfhi(s.z) + bfhi(d.z), 0.f); r = fmaf(hv, w1.y, r);
    hv = fmaxf(bflo(s.w) + bflo(d.w), 0.f); r = fmaf(hv, w1.z, r);
    hv = fmaxf(bfhi(s.w) + bfhi(d.w), 0.f); r = fmaf(hv, w1.w, r);
    return r;
}

__global__ __launch_bounds__(256) void k_edge(
    const __bf16* __restrict__ Ps, const __bf16* __restrict__ Pd,
    const int* __restrict__ src, const int* __restrict__ dst,
    const float* __restrict__ W2, const float* __restrict__ b2,
    float* __restrict__ out, int E)
{
    const int lane = threadIdx.x & 63;
    const int q = lane & 15;             // element slice
    const int g = lane >> 4;             // edge slot within wave
    const int wave = blockIdx.x * 4 + (threadIdx.x >> 6);
    const int nw = gridDim.x * 4;

    const float4* W2v = (const float4*)W2;
    const float4 wa0 = W2v[2 * q], wa1 = W2v[2 * q + 1];
    const float4 wb0 = W2v[32 + 2 * q], wb1 = W2v[32 + 2 * q + 1];
    const float bias = b2[0];

    for (int base = wave * 4; base < E; base += nw * 4) {
        const int e = base + g;
        float acc = 0.f;
        const bool valid = (e < E);
        if (valid) {
            const int s = src[e];
            const int d = dst[e];
            const uint4* ps = (const uint4*)(Ps + (size_t)s * HID);
            const uint4* pd = (const uint4*)(Pd + (size_t)d * HID);
            uint4 a0 = ps[q];       // elems 8q..8q+7
            uint4 a1 = ps[16 + q];  // elems 128+8q..
            uint4 c0 = pd[q];
            uint4 c1 = pd[16 + q];
            acc  = dot8(a0, c0, wa0, wa1);
            acc += dot8(a1, c1, wb0, wb1);
        }
#pragma unroll
        for (int m = 1; m < 16; m <<= 1) acc += __shfl_xor(acc, m, 64);
        if (q == 0 && valid) out[e] = acc + bias;
    }
}

// ---------------- launch -------------------------------------------------------
extern "C" void kernel_launch(void* const* d_in, const int* in_sizes, int n_in,
                              void* d_out, int out_size, void* d_ws, size_t ws_size,
                              hipStream_t stream) {
    const float* h_src = (const float*)d_in[0];
    const float* h_dst = (const float*)d_in[1];
    const int*   src   = (const int*)d_in[2];
    const int*   dst   = (const int*)d_in[3];
    const float* W1    = (const float*)d_in[4];
    const float* b1    = (const float*)d_in[5];
    const float* W2    = (const float*)d_in[6];
    const float* b2    = (const float*)d_in[7];
    float* out = (float*)d_out;

    const int E  = in_sizes[2];
    const int NN = in_sizes[0] / IN_FEATS;   // 100000

    // Workspace layout: [W1T bf16 256x256][Ps bf16 NNx256][Pd bf16 NNx256]
    __bf16* W1T = (__bf16*)d_ws;
    __bf16* Ps  = (__bf16*)((char*)d_ws + (size_t)(2 * IN_FEATS) * HID * sizeof(__bf16));
    __bf16* Pd  = Ps + (size_t)NN * HID;

    k_prep<<<2 * IN_FEATS, HID, 0, stream>>>(W1, W1T);
    dim3 gA(NN / 32, 2);
    k_proj<<<gA, 256, 0, stream>>>(h_src, h_dst, W1T, b1, Ps, Pd);
    k_edge<<<2048, 256, 0, stream>>>(Ps, Pd, src, dst, W2, b2, out, E);
}

// Round 4
// 338.374 us; speedup vs baseline: 1.0822x; 1.0822x over previous
//
#include <hip/hip_runtime.h>
#include <hip/hip_bf16.h>
#include <stdint.h>

#define IN_FEATS 128
#define HID 256

typedef __bf16 bf16x8 __attribute__((ext_vector_type(8)));
typedef float  f32x4  __attribute__((ext_vector_type(4)));

__device__ __forceinline__ unsigned pk2(float a, float b) {
    __bf16 ba = (__bf16)a, bb = (__bf16)b;
    unsigned short ua = __builtin_bit_cast(unsigned short, ba);
    unsigned short ub = __builtin_bit_cast(unsigned short, bb);
    return (unsigned)ua | ((unsigned)ub << 16);
}

// ---------------- Kernel 0: pack W1 [256][256] fp32 into MFMA-fragment order --
// W1P[((which*4+ks)*16 + nblk)*64 + lane][j] = bf16( W1[which*128+ks*32+(lane>>4)*8+j][nblk*16+(lane&15)] )
// so k_proj's B-fragment load is one wave-contiguous 1KB dwordx4 load.
__global__ void k_prep(const float* __restrict__ W1, __bf16* __restrict__ W1P) {
    int t = blockIdx.x * blockDim.x + threadIdx.x;   // 8192 threads
    int lane  = t & 63;
    int nblk  = (t >> 6) & 15;
    int ks    = (t >> 10) & 3;
    int which = (t >> 12) & 1;
    int qr = lane & 15, qg = lane >> 4;
    int n  = nblk * 16 + qr;
    int k0 = which * 128 + ks * 32 + qg * 8;
    bf16x8 v;
#pragma unroll
    for (int j = 0; j < 8; ++j)
        v[j] = (__bf16)W1[(size_t)(k0 + j) * HID + n];
    *(bf16x8*)(W1P + (size_t)t * 8) = v;
}

// ---------------- Kernel A: node projections -----------------------------------
// P_src[n,256] = h_src[n,:] @ W1[0:128,:] + b1   (blockIdx.y == 0)
// P_dst[n,256] = h_dst[n,:] @ W1[128:256,:]      (blockIdx.y == 1)
// Block 256 = 4 waves; block tile 32 rows x 256 cols; wave tile 32x64.
// B frags from pre-packed W1P (wave-contiguous). Epilogue packs 2 cols/u32.
__global__ __launch_bounds__(256) void k_proj(
    const float* __restrict__ hs, const float* __restrict__ hd,
    const __bf16* __restrict__ W1P, const float* __restrict__ b1,
    __bf16* __restrict__ Ps, __bf16* __restrict__ Pd)
{
    const int which = blockIdx.y;
    const float* __restrict__ h = which ? hd : hs;
    __bf16* __restrict__ P = which ? Pd : Ps;

    const int lane = threadIdx.x & 63;
    const int w    = threadIdx.x >> 6;   // wave 0..3
    const int n0   = w * 64;
    const int node0 = blockIdx.x * 32;
    const int qr = lane & 15;
    const int qg = lane >> 4;
    const bf16x8* __restrict__ W1Pv = (const bf16x8*)W1P;

    f32x4 acc[2][4];
#pragma unroll
    for (int m = 0; m < 2; ++m)
#pragma unroll
        for (int n = 0; n < 4; ++n) acc[m][n] = (f32x4){0.f, 0.f, 0.f, 0.f};

#pragma unroll
    for (int ks = 0; ks < 4; ++ks) {
        const int k0 = ks * 32 + qg * 8;
        bf16x8 a[2];
#pragma unroll
        for (int m = 0; m < 2; ++m) {
            const float* ap = h + (size_t)(node0 + m * 16 + qr) * IN_FEATS + k0;
            float4 f0 = *(const float4*)ap;
            float4 f1 = *(const float4*)(ap + 4);
            bf16x8 t;
            t[0] = (__bf16)f0.x; t[1] = (__bf16)f0.y; t[2] = (__bf16)f0.z; t[3] = (__bf16)f0.w;
            t[4] = (__bf16)f1.x; t[5] = (__bf16)f1.y; t[6] = (__bf16)f1.z; t[7] = (__bf16)f1.w;
            a[m] = t;
        }
#pragma unroll
        for (int n = 0; n < 4; ++n) {
            bf16x8 b = W1Pv[((size_t)(which * 4 + ks) * 16 + w * 4 + n) * 64 + lane];
#pragma unroll
            for (int m = 0; m < 2; ++m)
                acc[m][n] = __builtin_amdgcn_mfma_f32_16x16x32_bf16(a[m], b, acc[m][n], 0, 0, 0);
        }
    }

    // Epilogue: D layout col=lane&15, row=(lane>>4)*4+i. Pack col-pairs into u32:
    // lane^1 holds the partner column, same rows. Even lane stores rows i0={0,1},
    // odd lane rows {2,3} -> 16 u32 stores/thread, 32B contiguous per 8 lanes.
    const bool even = (qr & 1) == 0;
    const int i0 = even ? 0 : 2;
#pragma unroll
    for (int n = 0; n < 4; ++n) {
        const int col = n0 + n * 16 + qr;
        const float bias = which ? 0.f : b1[col];
#pragma unroll
        for (int m = 0; m < 2; ++m) {
            const int rowb = node0 + m * 16 + qg * 4;
            float v[4], o[4];
#pragma unroll
            for (int i = 0; i < 4; ++i) {
                v[i] = acc[m][n][i] + bias;
                o[i] = __shfl_xor(v[i], 1, 64);
            }
#pragma unroll
            for (int i = 0; i < 2; ++i) {
                const int r = i0 + i;
                unsigned wd = even ? pk2(v[r], o[r]) : pk2(o[r], v[r]);
                *(unsigned*)(P + (size_t)(rowb + r) * HID + (col & ~1)) = wd;
            }
        }
    }
}

// ---------------- Kernel B: edge scoring ---------------------------------------
// score[e] = b2 + sum_j relu(Ps[src[e]][j] + Pd[dst[e]][j]) * W2[j]
// Quarter-wave (16 lanes) per edge slot; 2 edges per slot per iteration so each
// thread keeps 8x16B loads (128B) in flight before the reduce dependency.
__device__ __forceinline__ float bflo(unsigned u) { return __uint_as_float(u << 16); }
__device__ __forceinline__ float bfhi(unsigned u) { return __uint_as_float(u & 0xffff0000u); }

__device__ __forceinline__ float dot8(uint4 s, uint4 d, float4 w0, float4 w1) {
    float r = 0.f, hv;
    hv = fmaxf(bflo(s.x) + bflo(d.x), 0.f); r = fmaf(hv, w0.x, r);
    hv = fmaxf(bfhi(s.x) + bfhi(d.x), 0.f); r = fmaf(hv, w0.y, r);
    hv = fmaxf(bflo(s.y) + bflo(d.y), 0.f); r = fmaf(hv, w0.z, r);
    hv = fmaxf(bfhi(s.y) + bfhi(d.y), 0.f); r = fmaf(hv, w0.w, r);
    hv = fmaxf(bflo(s.z) + bflo(d.z), 0.f); r = fmaf(hv, w1.x, r);
    hv = fmaxf(bfhi(s.z) + bfhi(d.z), 0.f); r = fmaf(hv, w1.y, r);
    hv = fmaxf(bflo(s.w) + bflo(d.w), 0.f); r = fmaf(hv, w1.z, r);
    hv = fmaxf(bfhi(s.w) + bfhi(d.w), 0.f); r = fmaf(hv, w1.w, r);
    return r;
}

__global__ __launch_bounds__(256) void k_edge(
    const __bf16* __restrict__ Ps, const __bf16* __restrict__ Pd,
    const int* __restrict__ src, const int* __restrict__ dst,
    const float* __restrict__ W2, const float* __restrict__ b2,
    float* __restrict__ out, int E)
{
    const int lane = threadIdx.x & 63;
    const int q = lane & 15;             // element slice
    const int g = lane >> 4;             // edge slot within wave
    const int wave = blockIdx.x * 4 + (threadIdx.x >> 6);
    const int nw = gridDim.x * 4;

    const float4* W2v = (const float4*)W2;
    const float4 wa0 = W2v[2 * q], wa1 = W2v[2 * q + 1];
    const float4 wb0 = W2v[32 + 2 * q], wb1 = W2v[32 + 2 * q + 1];
    const float bias = b2[0];

    for (int base = wave * 8; base < E; base += nw * 8) {
        const int e0 = base + g;
        const int e1 = base + 4 + g;
        const bool v0 = (e0 < E), v1 = (e1 < E);
        float acc0 = 0.f, acc1 = 0.f;
        if (v0) {
            const uint4* ps = (const uint4*)(Ps + (size_t)src[e0] * HID);
            const uint4* pd = (const uint4*)(Pd + (size_t)dst[e0] * HID);
            uint4 a0 = ps[q], a1 = ps[16 + q], c0 = pd[q], c1 = pd[16 + q];
            if (v1) {
                const uint4* ps1 = (const uint4*)(Ps + (size_t)src[e1] * HID);
                const uint4* pd1 = (const uint4*)(Pd + (size_t)dst[e1] * HID);
                uint4 b0 = ps1[q], b1v = ps1[16 + q], d0 = pd1[q], d1 = pd1[16 + q];
                acc0  = dot8(a0, c0, wa0, wa1);
                acc0 += dot8(a1, c1, wb0, wb1);
                acc1  = dot8(b0, d0, wa0, wa1);
                acc1 += dot8(b1v, d1, wb0, wb1);
            } else {
                acc0  = dot8(a0, c0, wa0, wa1);
                acc0 += dot8(a1, c1, wb0, wb1);
            }
        }
#pragma unroll
        for (int m = 1; m < 16; m <<= 1) {
            acc0 += __shfl_xor(acc0, m, 64);
            acc1 += __shfl_xor(acc1, m, 64);
        }
        if (q == 0) {
            if (v0) out[e0] = acc0 + bias;
            if (v1) out[e1] = acc1 + bias;
        }
    }
}

// ---------------- launch -------------------------------------------------------
extern "C" void kernel_launch(void* const* d_in, const int* in_sizes, int n_in,
                              void* d_out, int out_size, void* d_ws, size_t ws_size,
                              hipStream_t stream) {
    const float* h_src = (const float*)d_in[0];
    const float* h_dst = (const float*)d_in[1];
    const int*   src   = (const int*)d_in[2];
    const int*   dst   = (const int*)d_in[3];
    const float* W1    = (const float*)d_in[4];
    const float* b1    = (const float*)d_in[5];
    const float* W2    = (const float*)d_in[6];
    const float* b2    = (const float*)d_in[7];
    float* out = (float*)d_out;

    const int E  = in_sizes[2];
    const int NN = in_sizes[0] / IN_FEATS;   // 100000

    // Workspace layout: [W1P bf16 256x256 packed][Ps bf16 NNx256][Pd bf16 NNx256]
    __bf16* W1P = (__bf16*)d_ws;
    __bf16* Ps  = (__bf16*)((char*)d_ws + (size_t)(2 * IN_FEATS) * HID * sizeof(__bf16));
    __bf16* Pd  = Ps + (size_t)NN * HID;

    k_prep<<<32, 256, 0, stream>>>(W1, W1P);
    dim3 gA(NN / 32, 2);
    k_proj<<<gA, 256, 0, stream>>>(h_src, h_dst, W1P, b1, Ps, Pd);
    k_edge<<<2048, 256, 0, stream>>>(Ps, Pd, src, dst, W2, b2, out, E);
}